// Round 6
// baseline (502.970 us; speedup 1.0000x reference)
//
#include <hip/hip_runtime.h>

typedef unsigned short u16;
typedef __attribute__((ext_vector_type(8))) short bf16x8;
typedef __attribute__((ext_vector_type(4))) float f32x4;

__device__ __forceinline__ u16 f2bf(float f) {
    unsigned x = __float_as_uint(f);
    unsigned lsb = (x >> 16) & 1u;
    x += 0x7fffu + lsb;            // round-to-nearest-even
    return (u16)(x >> 16);
}

#define N_NODES 2048
#define D_EMB 64
#define P_DIM 32
#define NS_STOPS 512
#define IN_LEN 4131   // 32 + 2048 + 2048 + 3
#define KGEMM 4096

// ---------------- keep mask ----------------
__global__ void k_keep(const int* __restrict__ stops, int* __restrict__ keep) {
    __shared__ int s[NS_STOPS];
    int t = threadIdx.x;
    for (int u = t; u < NS_STOPS; u += 256) s[u] = stops[u];
    __syncthreads();
    int node = blockIdx.x * 256 + t;
    int f = 0;
    for (int u = 0; u < NS_STOPS; ++u) f |= (s[u] == node);
    keep[node] = f;
}

// ---------------- row-normalized embeddings (fp32) ----------------
__global__ void k_xn(const float* __restrict__ emb, float* __restrict__ xn) {
    int t = threadIdx.x;
    int row = blockIdx.x * 4 + (t >> 6);
    int d = t & 63;
    float v = emb[row * D_EMB + d];
    float s = v * v;
    #pragma unroll
    for (int off = 32; off; off >>= 1) s += __shfl_xor(s, off, 64);
    float nm = fmaxf(sqrtf(s), 1e-8f);
    xn[row * D_EMB + d] = v / nm;
}

// ---------------- cosine graph + mean aggregation (agg/deg) ----------------
__global__ __launch_bounds__(256) void k_agg(const float* __restrict__ xn, const float* __restrict__ emb,
                                             const int* __restrict__ keep, float* __restrict__ aggd) {
    int i = blockIdx.x, t = threadIdx.x;
    __shared__ float xi[D_EMB];
    __shared__ float aggL[D_EMB];
    __shared__ int degL;
    int ki = keep[i];            // block-uniform
    if (t < D_EMB) { xi[t] = xn[i * D_EMB + t]; aggL[t] = 0.f; }
    if (t == 0) degL = 0;
    __syncthreads();
    if (ki) {
        for (int j = t; j < N_NODES; j += 256) {
            if (!keep[j] || j == i) continue;
            const float* xj = &xn[j * D_EMB];
            float dot = 0.f;
            #pragma unroll
            for (int d = 0; d < D_EMB; ++d) dot += xi[d] * xj[d];
            if (dot > 0.5f) {
                atomicAdd(&degL, 1);
                #pragma unroll
                for (int d = 0; d < D_EMB; ++d) atomicAdd(&aggL[d], emb[j * D_EMB + d]);
            }
        }
    }
    __syncthreads();
    if (t < D_EMB) {
        float deg = fmaxf((float)degL, 1.0f);
        aggd[i * D_EMB + t] = ki ? (aggL[t] / deg) : 0.f;
    }
}

// ---------------- pref = aggd@lin_l^T + b + emb@lin_r^T; a,b vectors ----------------
__global__ __launch_bounds__(64) void k_pref(const float* __restrict__ aggd, const float* __restrict__ emb,
                                             const float* __restrict__ lin_l_w, const float* __restrict__ lin_l_b,
                                             const float* __restrict__ lin_r_w, const float* __restrict__ edge_w,
                                             float* __restrict__ pref, float* __restrict__ av, float* __restrict__ bv) {
    int i = blockIdx.x, t = threadIdx.x;   // block = 1 wave
    float pv = 0.f;
    if (t < P_DIM) {
        float s = lin_l_b[t];
        #pragma unroll
        for (int d = 0; d < D_EMB; ++d) {
            s += aggd[i * D_EMB + d] * lin_l_w[t * D_EMB + d];
            s += emb[i * D_EMB + d] * lin_r_w[t * D_EMB + d];
        }
        pref[i * P_DIM + t] = s;
        pv = s;
    }
    float a = (t < P_DIM) ? pv * edge_w[t] : 0.f;
    float b = (t < P_DIM) ? pv * edge_w[P_DIM + t] : 0.f;
    #pragma unroll
    for (int off = 32; off; off >>= 1) { a += __shfl_xor(a, off, 64); b += __shfl_xor(b, off, 64); }
    if (t == 0) { av[i] = a; bv[i] = b; }
}

// ---------------- main bf16 GEMM: C[2048x2048] = [es|dist] @ comb_w[:,32:4128]^T ----------------
// Inputs FP32, converted to bf16 during LDS staging. A virtual: es_ik = leaky(av[i]+bv[k]+eb)
// for k<2048, dist[i][k-2048] for k>=2048. B from comb_w (f32, row stride 4131, offset 32).
// C accumulators written as FP32 directly into d_out (f32 output dtype); epilogue in place.
__global__ __launch_bounds__(256) void k_gemm(const float* __restrict__ dist, const float* __restrict__ comb_w,
                                              const float* __restrict__ av, const float* __restrict__ bv,
                                              const float* __restrict__ edge_b, float* __restrict__ Cout) {
    __shared__ __attribute__((aligned(16))) short As[128 * 64];
    __shared__ __attribute__((aligned(16))) short Bs[128 * 64];
    int t = threadIdx.x;
    int tileM = blockIdx.y * 128, tileN = blockIdx.x * 128;
    int lane = t & 63;
    int wid = t >> 6;
    int waveM = wid & 1, waveN = wid >> 1;
    int l16 = lane & 15, quad = lane >> 4;

    f32x4 acc[4][4];
    #pragma unroll
    for (int a_ = 0; a_ < 4; ++a_)
        #pragma unroll
        for (int b_ = 0; b_ < 4; ++b_) acc[a_][b_] = (f32x4){0.f, 0.f, 0.f, 0.f};

    int r = t >> 1;           // 0..127 staging row
    int half = t & 1;         // 32-col half
    float a_base = av[tileM + r] + edge_b[0];
    const float* distrow = dist + (size_t)(tileM + r) * 2048 + half * 32;
    const float* brow = comb_w + (size_t)(tileN + r) * IN_LEN + 32 + half * 32;
    short* as_dst = &As[r * 64 + half * 32];
    short* bs_dst = &Bs[r * 64 + half * 32];

    for (int k0 = 0; k0 < KGEMM; k0 += 64) {
        __syncthreads();
        if (k0 < 2048) {
            #pragma unroll
            for (int u = 0; u < 4; ++u) {
                bf16x8 v;
                #pragma unroll
                for (int j = 0; j < 8; ++j) {
                    float s = a_base + bv[k0 + half * 32 + u * 8 + j];
                    s = (s >= 0.f) ? s : 0.01f * s;
                    v[j] = (short)f2bf(s);
                }
                *(bf16x8*)&as_dst[u * 8] = v;
            }
        } else {
            const float* src = distrow + (k0 - 2048);   // 32B-aligned
            #pragma unroll
            for (int u = 0; u < 4; ++u) {
                const f32x4* sp = (const f32x4*)(src + u * 8);
                f32x4 f0 = sp[0], f1 = sp[1];
                bf16x8 v;
                #pragma unroll
                for (int j = 0; j < 4; ++j) { v[j] = (short)f2bf(f0[j]); v[4 + j] = (short)f2bf(f1[j]); }
                *(bf16x8*)&as_dst[u * 8] = v;
            }
        }
        {
            const float* src = brow + k0;               // 4B-aligned only
            #pragma unroll
            for (int u = 0; u < 4; ++u) {
                float tmpf[8];
                __builtin_memcpy(tmpf, src + u * 8, 32);
                bf16x8 v;
                #pragma unroll
                for (int j = 0; j < 8; ++j) v[j] = (short)f2bf(tmpf[j]);
                *(bf16x8*)&bs_dst[u * 8] = v;
            }
        }
        __syncthreads();
        #pragma unroll
        for (int kk = 0; kk < 64; kk += 32) {
            bf16x8 af[4], bfr[4];
            #pragma unroll
            for (int mi = 0; mi < 4; ++mi)
                af[mi] = *(const bf16x8*)&As[(waveM * 64 + mi * 16 + l16) * 64 + kk + quad * 8];
            #pragma unroll
            for (int ni = 0; ni < 4; ++ni)
                bfr[ni] = *(const bf16x8*)&Bs[(waveN * 64 + ni * 16 + l16) * 64 + kk + quad * 8];
            #pragma unroll
            for (int mi = 0; mi < 4; ++mi)
                #pragma unroll
                for (int ni = 0; ni < 4; ++ni)
                    acc[mi][ni] = __builtin_amdgcn_mfma_f32_16x16x32_bf16(af[mi], bfr[ni], acc[mi][ni], 0, 0, 0);
        }
    }
    #pragma unroll
    for (int mi = 0; mi < 4; ++mi)
        #pragma unroll
        for (int ni = 0; ni < 4; ++ni) {
            int row = tileM + waveM * 64 + mi * 16 + quad * 4;
            int col = tileN + waveN * 64 + ni * 16 + l16;
            float* cp = Cout + (size_t)row * N_NODES + col;
            #pragma unroll
            for (int rr = 0; rr < 4; ++rr) cp[(size_t)rr * N_NODES] = acc[mi][ni][rr];
        }
}

// ---------------- epilogue: + pref@Wp^T + scalar feats + bias, then log-softmax (in place, f32) ----------------
__global__ __launch_bounds__(256) void k_epi(const float* __restrict__ comb_w,
                                             const float* __restrict__ comb_b, const float* __restrict__ pref,
                                             const int* __restrict__ keep, const int* __restrict__ wk_p,
                                             const int* __restrict__ vh_p, float* __restrict__ out) {
    int i = blockIdx.x, t = threadIdx.x;
    __shared__ float prefL[P_DIM];
    __shared__ float redmax[4], redsum[4];
    if (t < P_DIM) prefL[t] = pref[i * P_DIM + t];
    __syncthreads();
    float wk = (float)wk_p[0], vh = (float)vh_p[0];
    float ki = keep[i] ? 1.f : 0.f;
    float vals[8];
    float vmax = -1e30f;
    #pragma unroll
    for (int u = 0; u < 8; ++u) {
        int j = t + u * 256;
        const float* wr = comb_w + (size_t)j * IN_LEN;
        float dot = 0.f;
        #pragma unroll
        for (int p = 0; p < P_DIM; ++p) dot += prefL[p] * wr[p];
        float v = out[(size_t)i * N_NODES + j] + dot + wk * wr[4128] + vh * wr[4129] +
                  ki * wr[4130] + comb_b[j];
        vals[u] = v;
        vmax = fmaxf(vmax, v);
    }
    #pragma unroll
    for (int off = 32; off; off >>= 1) vmax = fmaxf(vmax, __shfl_xor(vmax, off, 64));
    if ((t & 63) == 0) redmax[t >> 6] = vmax;
    __syncthreads();
    vmax = fmaxf(fmaxf(redmax[0], redmax[1]), fmaxf(redmax[2], redmax[3]));
    float se = 0.f;
    #pragma unroll
    for (int u = 0; u < 8; ++u) se += expf(vals[u] - vmax);
    #pragma unroll
    for (int off = 32; off; off >>= 1) se += __shfl_xor(se, off, 64);
    if ((t & 63) == 0) redsum[t >> 6] = se;
    __syncthreads();
    se = redsum[0] + redsum[1] + redsum[2] + redsum[3];
    float lz = vmax + logf(se);
    #pragma unroll
    for (int u = 0; u < 8; ++u) out[(size_t)i * N_NODES + t + u * 256] = vals[u] - lz;
}

extern "C" void kernel_launch(void* const* d_in, const int* in_sizes, int n_in,
                              void* d_out, int out_size, void* d_ws, size_t ws_size,
                              hipStream_t stream) {
    const float* dist    = (const float*)d_in[0];
    const float* emb     = (const float*)d_in[1];
    const float* lin_l_w = (const float*)d_in[2];
    const float* lin_l_b = (const float*)d_in[3];
    const float* lin_r_w = (const float*)d_in[4];
    const float* edge_w  = (const float*)d_in[5];
    const float* edge_b  = (const float*)d_in[6];
    const float* comb_w  = (const float*)d_in[7];
    const float* comb_b  = (const float*)d_in[8];
    const int* stops     = (const int*)d_in[9];
    const int* wk        = (const int*)d_in[10];
    const int* vh        = (const int*)d_in[11];

    // workspace: only ~1.35 MB used
    char* ws = (char*)d_ws;
    float* xn    = (float*)(ws + 0);          // 2048*64*4 = 524288
    int*   keep  = (int*)(ws + 524288);       // 2048*4    = 8192
    float* aggd  = (float*)(ws + 532480);     // 2048*64*4 = 524288
    float* pref  = (float*)(ws + 1056768);    // 2048*32*4 = 262144
    float* av    = (float*)(ws + 1318912);    // 8192
    float* bv    = (float*)(ws + 1327104);    // 8192
    float* out   = (float*)d_out;             // f32 [2048,2048]; holds C between k_gemm and k_epi

    hipLaunchKernelGGL(k_keep, dim3(8),      dim3(256), 0, stream, stops, keep);
    hipLaunchKernelGGL(k_xn,   dim3(512),    dim3(256), 0, stream, emb, xn);
    hipLaunchKernelGGL(k_agg,  dim3(2048),   dim3(256), 0, stream, xn, emb, keep, aggd);
    hipLaunchKernelGGL(k_pref, dim3(2048),   dim3(64),  0, stream, aggd, emb, lin_l_w, lin_l_b, lin_r_w, edge_w, pref, av, bv);
    hipLaunchKernelGGL(k_gemm, dim3(16, 16), dim3(256), 0, stream, dist, comb_w, av, bv, edge_b, out);
    hipLaunchKernelGGL(k_epi,  dim3(2048),   dim3(256), 0, stream, comb_w, comb_b, pref, keep, wk, vh, out);
}

// Round 7
// 468.341 us; speedup vs baseline: 1.0739x; 1.0739x over previous
//
#include <hip/hip_runtime.h>

typedef unsigned short u16;
typedef __attribute__((ext_vector_type(8))) short bf16x8;
typedef __attribute__((ext_vector_type(4))) float f32x4;

__device__ __forceinline__ u16 f2bf(float f) {
    unsigned x = __float_as_uint(f);
    unsigned lsb = (x >> 16) & 1u;
    x += 0x7fffu + lsb;            // round-to-nearest-even
    return (u16)(x >> 16);
}

#define N_NODES 2048
#define D_EMB 64
#define P_DIM 32
#define NS_STOPS 512
#define IN_LEN 4131   // 32 + 2048 + 2048 + 3
#define KGEMM 4096

// 16B-chunk XOR swizzle: row has 8 chunks of 8 shorts; physical short offset of chunk c in row
#define SWZ(row, c) ((((row) * 8) + ((c) ^ ((row) & 7))) * 8)

// ---------------- keep mask ----------------
__global__ void k_keep(const int* __restrict__ stops, int* __restrict__ keep) {
    __shared__ int s[NS_STOPS];
    int t = threadIdx.x;
    for (int u = t; u < NS_STOPS; u += 256) s[u] = stops[u];
    __syncthreads();
    int node = blockIdx.x * 256 + t;
    int f = 0;
    for (int u = 0; u < NS_STOPS; ++u) f |= (s[u] == node);
    keep[node] = f;
}

// ---------------- row-normalized embeddings (fp32) ----------------
__global__ void k_xn(const float* __restrict__ emb, float* __restrict__ xn) {
    int t = threadIdx.x;
    int row = blockIdx.x * 4 + (t >> 6);
    int d = t & 63;
    float v = emb[row * D_EMB + d];
    float s = v * v;
    #pragma unroll
    for (int off = 32; off; off >>= 1) s += __shfl_xor(s, off, 64);
    float nm = fmaxf(sqrtf(s), 1e-8f);
    xn[row * D_EMB + d] = v / nm;
}

// ---------------- cosine graph + mean aggregation (agg/deg) ----------------
__global__ __launch_bounds__(256) void k_agg(const float* __restrict__ xn, const float* __restrict__ emb,
                                             const int* __restrict__ keep, float* __restrict__ aggd) {
    int i = blockIdx.x, t = threadIdx.x;
    __shared__ float xi[D_EMB];
    __shared__ float aggL[D_EMB];
    __shared__ int degL;
    int ki = keep[i];            // block-uniform
    if (t < D_EMB) { xi[t] = xn[i * D_EMB + t]; aggL[t] = 0.f; }
    if (t == 0) degL = 0;
    __syncthreads();
    if (ki) {
        for (int j = t; j < N_NODES; j += 256) {
            if (!keep[j] || j == i) continue;
            const float* xj = &xn[j * D_EMB];
            float dot = 0.f;
            #pragma unroll
            for (int d = 0; d < D_EMB; ++d) dot += xi[d] * xj[d];
            if (dot > 0.5f) {
                atomicAdd(&degL, 1);
                #pragma unroll
                for (int d = 0; d < D_EMB; ++d) atomicAdd(&aggL[d], emb[j * D_EMB + d]);
            }
        }
    }
    __syncthreads();
    if (t < D_EMB) {
        float deg = fmaxf((float)degL, 1.0f);
        aggd[i * D_EMB + t] = ki ? (aggL[t] / deg) : 0.f;
    }
}

// ---------------- pref = aggd@lin_l^T + b + emb@lin_r^T; a,b vectors ----------------
__global__ __launch_bounds__(64) void k_pref(const float* __restrict__ aggd, const float* __restrict__ emb,
                                             const float* __restrict__ lin_l_w, const float* __restrict__ lin_l_b,
                                             const float* __restrict__ lin_r_w, const float* __restrict__ edge_w,
                                             float* __restrict__ pref, float* __restrict__ av, float* __restrict__ bv) {
    int i = blockIdx.x, t = threadIdx.x;   // block = 1 wave
    float pv = 0.f;
    if (t < P_DIM) {
        float s = lin_l_b[t];
        #pragma unroll
        for (int d = 0; d < D_EMB; ++d) {
            s += aggd[i * D_EMB + d] * lin_l_w[t * D_EMB + d];
            s += emb[i * D_EMB + d] * lin_r_w[t * D_EMB + d];
        }
        pref[i * P_DIM + t] = s;
        pv = s;
    }
    float a = (t < P_DIM) ? pv * edge_w[t] : 0.f;
    float b = (t < P_DIM) ? pv * edge_w[P_DIM + t] : 0.f;
    #pragma unroll
    for (int off = 32; off; off >>= 1) { a += __shfl_xor(a, off, 64); b += __shfl_xor(b, off, 64); }
    if (t == 0) { av[i] = a; bv[i] = b; }
}

// ---------------- main bf16 GEMM: C[2048x2048] = [es|dist] @ comb_w[:,32:4128]^T ----------------
// f32 inputs converted to bf16 at LDS-staging time. Register-prefetch pipeline:
// global f32 loads for tile k0+64 are issued before the MFMA phase of tile k0.
// LDS XOR-swizzled in 16B chunks -> conflict-free ds_read_b128/ds_write_b128.
__global__ __launch_bounds__(256) void k_gemm(const float* __restrict__ dist, const float* __restrict__ comb_w,
                                              const float* __restrict__ av, const float* __restrict__ bv,
                                              const float* __restrict__ edge_b, float* __restrict__ Cout) {
    __shared__ __attribute__((aligned(16))) short As[128 * 64];
    __shared__ __attribute__((aligned(16))) short Bs[128 * 64];
    int t = threadIdx.x;
    int tileM = blockIdx.y * 128, tileN = blockIdx.x * 128;
    int lane = t & 63;
    int wid = t >> 6;
    int waveM = wid & 1, waveN = wid >> 1;
    int l16 = lane & 15, quad = lane >> 4;

    f32x4 acc[4][4];
    #pragma unroll
    for (int a_ = 0; a_ < 4; ++a_)
        #pragma unroll
        for (int b_ = 0; b_ < 4; ++b_) acc[a_][b_] = (f32x4){0.f, 0.f, 0.f, 0.f};

    int r = t >> 1;           // 0..127 staging row
    int half = t & 1;         // 32-col half
    float a_base = av[tileM + r] + edge_b[0];
    const float* distrow = dist + (size_t)(tileM + r) * 2048 + half * 32;
    const float* brow = comb_w + (size_t)(tileN + r) * IN_LEN + 32 + half * 32;

    f32x4 pa[8], pb[8];       // prefetch registers (32 A-f32 + 32 B-f32 per thread)

    auto loadA = [&](int k0) {
        if (k0 < 2048) {
            const f32x4* bp = (const f32x4*)&bv[k0 + half * 32];     // 128B-aligned
            #pragma unroll
            for (int u = 0; u < 8; ++u) pa[u] = bp[u];
        } else {
            const f32x4* sp = (const f32x4*)(distrow + (k0 - 2048)); // 128B-aligned
            #pragma unroll
            for (int u = 0; u < 8; ++u) pa[u] = sp[u];
        }
    };
    auto loadB = [&](int k0) {
        const float* src = brow + k0;                                // 4B-aligned
        #pragma unroll
        for (int u = 0; u < 8; ++u) __builtin_memcpy(&pb[u], src + u * 4, 16);
    };
    auto storeAB = [&](int k0) {
        bool es = (k0 < 2048);
        #pragma unroll
        for (int u = 0; u < 4; ++u) {
            f32x4 f0 = pa[2 * u], f1 = pa[2 * u + 1];
            bf16x8 v;
            #pragma unroll
            for (int j = 0; j < 4; ++j) {
                float s0 = f0[j], s1 = f1[j];
                if (es) {
                    s0 += a_base; s0 = (s0 >= 0.f) ? s0 : 0.01f * s0;
                    s1 += a_base; s1 = (s1 >= 0.f) ? s1 : 0.01f * s1;
                }
                v[j] = (short)f2bf(s0);
                v[4 + j] = (short)f2bf(s1);
            }
            *(bf16x8*)&As[SWZ(r, half * 4 + u)] = v;
        }
        #pragma unroll
        for (int u = 0; u < 4; ++u) {
            f32x4 f0 = pb[2 * u], f1 = pb[2 * u + 1];
            bf16x8 v;
            #pragma unroll
            for (int j = 0; j < 4; ++j) { v[j] = (short)f2bf(f0[j]); v[4 + j] = (short)f2bf(f1[j]); }
            *(bf16x8*)&Bs[SWZ(r, half * 4 + u)] = v;
        }
    };

    loadA(0); loadB(0);
    for (int k0 = 0; k0 < KGEMM; k0 += 64) {
        __syncthreads();                 // previous tile's LDS consumers done
        storeAB(k0);                     // waits on prefetch regs, converts, writes LDS
        __syncthreads();                 // tile ready
        if (k0 + 64 < KGEMM) { loadA(k0 + 64); loadB(k0 + 64); }   // issue next loads early
        #pragma unroll
        for (int kk = 0; kk < 64; kk += 32) {
            int cbase = kk >> 3;         // chunk base: 0 or 4
            bf16x8 af[4], bfr[4];
            #pragma unroll
            for (int mi = 0; mi < 4; ++mi) {
                int row = waveM * 64 + mi * 16 + l16;
                af[mi] = *(const bf16x8*)&As[SWZ(row, cbase + quad)];
            }
            #pragma unroll
            for (int ni = 0; ni < 4; ++ni) {
                int row = waveN * 64 + ni * 16 + l16;
                bfr[ni] = *(const bf16x8*)&Bs[SWZ(row, cbase + quad)];
            }
            #pragma unroll
            for (int mi = 0; mi < 4; ++mi)
                #pragma unroll
                for (int ni = 0; ni < 4; ++ni)
                    acc[mi][ni] = __builtin_amdgcn_mfma_f32_16x16x32_bf16(af[mi], bfr[ni], acc[mi][ni], 0, 0, 0);
        }
    }
    #pragma unroll
    for (int mi = 0; mi < 4; ++mi)
        #pragma unroll
        for (int ni = 0; ni < 4; ++ni) {
            int row = tileM + waveM * 64 + mi * 16 + quad * 4;
            int col = tileN + waveN * 64 + ni * 16 + l16;
            float* cp = Cout + (size_t)row * N_NODES + col;
            #pragma unroll
            for (int rr = 0; rr < 4; ++rr) cp[(size_t)rr * N_NODES] = acc[mi][ni][rr];
        }
}

// ---------------- epilogue: + pref@Wp^T + scalar feats + bias, then log-softmax (in place, f32) ----------------
__global__ __launch_bounds__(256) void k_epi(const float* __restrict__ comb_w,
                                             const float* __restrict__ comb_b, const float* __restrict__ pref,
                                             const int* __restrict__ keep, const int* __restrict__ wk_p,
                                             const int* __restrict__ vh_p, float* __restrict__ out) {
    int i = blockIdx.x, t = threadIdx.x;
    __shared__ float prefL[P_DIM];
    __shared__ float redmax[4], redsum[4];
    if (t < P_DIM) prefL[t] = pref[i * P_DIM + t];
    __syncthreads();
    float wk = (float)wk_p[0], vh = (float)vh_p[0];
    float ki = keep[i] ? 1.f : 0.f;
    float vals[8];
    float vmax = -1e30f;
    #pragma unroll
    for (int u = 0; u < 8; ++u) {
        int j = t + u * 256;
        const float* wr = comb_w + (size_t)j * IN_LEN;
        float dot = 0.f;
        #pragma unroll
        for (int p = 0; p < P_DIM; ++p) dot += prefL[p] * wr[p];
        float v = out[(size_t)i * N_NODES + j] + dot + wk * wr[4128] + vh * wr[4129] +
                  ki * wr[4130] + comb_b[j];
        vals[u] = v;
        vmax = fmaxf(vmax, v);
    }
    #pragma unroll
    for (int off = 32; off; off >>= 1) vmax = fmaxf(vmax, __shfl_xor(vmax, off, 64));
    if ((t & 63) == 0) redmax[t >> 6] = vmax;
    __syncthreads();
    vmax = fmaxf(fmaxf(redmax[0], redmax[1]), fmaxf(redmax[2], redmax[3]));
    float se = 0.f;
    #pragma unroll
    for (int u = 0; u < 8; ++u) se += expf(vals[u] - vmax);
    #pragma unroll
    for (int off = 32; off; off >>= 1) se += __shfl_xor(se, off, 64);
    if ((t & 63) == 0) redsum[t >> 6] = se;
    __syncthreads();
    se = redsum[0] + redsum[1] + redsum[2] + redsum[3];
    float lz = vmax + logf(se);
    #pragma unroll
    for (int u = 0; u < 8; ++u) out[(size_t)i * N_NODES + t + u * 256] = vals[u] - lz;
}

extern "C" void kernel_launch(void* const* d_in, const int* in_sizes, int n_in,
                              void* d_out, int out_size, void* d_ws, size_t ws_size,
                              hipStream_t stream) {
    const float* dist    = (const float*)d_in[0];
    const float* emb     = (const float*)d_in[1];
    const float* lin_l_w = (const float*)d_in[2];
    const float* lin_l_b = (const float*)d_in[3];
    const float* lin_r_w = (const float*)d_in[4];
    const float* edge_w  = (const float*)d_in[5];
    const float* edge_b  = (const float*)d_in[6];
    const float* comb_w  = (const float*)d_in[7];
    const float* comb_b  = (const float*)d_in[8];
    const int* stops     = (const int*)d_in[9];
    const int* wk        = (const int*)d_in[10];
    const int* vh        = (const int*)d_in[11];

    // workspace: only ~1.35 MB used
    char* ws = (char*)d_ws;
    float* xn    = (float*)(ws + 0);          // 2048*64*4 = 524288
    int*   keep  = (int*)(ws + 524288);       // 2048*4    = 8192
    float* aggd  = (float*)(ws + 532480);     // 2048*64*4 = 524288
    float* pref  = (float*)(ws + 1056768);    // 2048*32*4 = 262144
    float* av    = (float*)(ws + 1318912);    // 8192
    float* bv    = (float*)(ws + 1327104);    // 8192
    float* out   = (float*)d_out;             // f32 [2048,2048]; holds C between k_gemm and k_epi

    hipLaunchKernelGGL(k_keep, dim3(8),      dim3(256), 0, stream, stops, keep);
    hipLaunchKernelGGL(k_xn,   dim3(512),    dim3(256), 0, stream, emb, xn);
    hipLaunchKernelGGL(k_agg,  dim3(2048),   dim3(256), 0, stream, xn, emb, keep, aggd);
    hipLaunchKernelGGL(k_pref, dim3(2048),   dim3(64),  0, stream, aggd, emb, lin_l_w, lin_l_b, lin_r_w, edge_w, pref, av, bv);
    hipLaunchKernelGGL(k_gemm, dim3(16, 16), dim3(256), 0, stream, dist, comb_w, av, bv, edge_b, out);
    hipLaunchKernelGGL(k_epi,  dim3(2048),   dim3(256), 0, stream, comb_w, comb_b, pref, keep, wk, vh, out);
}

// Round 8
// 298.952 us; speedup vs baseline: 1.6824x; 1.5666x over previous
//
#include <hip/hip_runtime.h>

typedef unsigned short u16;
typedef __attribute__((ext_vector_type(8))) short bf16x8;
typedef __attribute__((ext_vector_type(4))) float f32x4;

// round-to-nearest (ties away): 2 VALU ops, max err 0.5 ulp
__device__ __forceinline__ u16 f2bf(float f) {
    return (u16)((__float_as_uint(f) + 0x8000u) >> 16);
}

#define N_NODES 2048
#define D_EMB 64
#define P_DIM 32
#define NS_STOPS 512
#define IN_LEN 4131   // 32 + 2048 + 2048 + 3
#define KGEMM 4160    // 2048 es + 2048 dist + 32 pref + 32 zero-pad

// 16B-chunk XOR swizzle: row has 8 chunks of 8 shorts
#define SWZ(row, c) ((((row) * 8) + ((c) ^ ((row) & 7))) * 8)

// ---------------- keep mask ----------------
__global__ void k_keep(const int* __restrict__ stops, int* __restrict__ keep) {
    __shared__ int s[NS_STOPS];
    int t = threadIdx.x;
    for (int u = t; u < NS_STOPS; u += 256) s[u] = stops[u];
    __syncthreads();
    int node = blockIdx.x * 256 + t;
    int f = 0;
    for (int u = 0; u < NS_STOPS; ++u) f |= (s[u] == node);
    keep[node] = f;
}

// ---------------- row-normalized embeddings (fp32) ----------------
__global__ void k_xn(const float* __restrict__ emb, float* __restrict__ xn) {
    int t = threadIdx.x;
    int row = blockIdx.x * 4 + (t >> 6);
    int d = t & 63;
    float v = emb[row * D_EMB + d];
    float s = v * v;
    #pragma unroll
    for (int off = 32; off; off >>= 1) s += __shfl_xor(s, off, 64);
    float nm = fmaxf(sqrtf(s), 1e-8f);
    xn[row * D_EMB + d] = v / nm;
}

// ---------------- cosine graph + mean aggregation ----------------
__global__ __launch_bounds__(256) void k_agg(const float* __restrict__ xn, const float* __restrict__ emb,
                                             const int* __restrict__ keep, float* __restrict__ aggd) {
    int i = blockIdx.x, t = threadIdx.x;
    __shared__ float xi[D_EMB];
    __shared__ float aggL[D_EMB];
    __shared__ int degL;
    int ki = keep[i];            // block-uniform
    if (t < D_EMB) { xi[t] = xn[i * D_EMB + t]; aggL[t] = 0.f; }
    if (t == 0) degL = 0;
    __syncthreads();
    if (ki) {
        for (int j = t; j < N_NODES; j += 256) {
            if (!keep[j] || j == i) continue;
            const float* xj = &xn[j * D_EMB];
            float dot = 0.f;
            #pragma unroll
            for (int d = 0; d < D_EMB; ++d) dot += xi[d] * xj[d];
            if (dot > 0.5f) {
                atomicAdd(&degL, 1);
                #pragma unroll
                for (int d = 0; d < D_EMB; ++d) atomicAdd(&aggL[d], emb[j * D_EMB + d]);
            }
        }
    }
    __syncthreads();
    if (t < D_EMB) {
        float deg = fmaxf((float)degL, 1.0f);
        aggd[i * D_EMB + t] = ki ? (aggL[t] / deg) : 0.f;
    }
}

// ---------------- pref + a,b vectors ----------------
__global__ __launch_bounds__(64) void k_pref(const float* __restrict__ aggd, const float* __restrict__ emb,
                                             const float* __restrict__ lin_l_w, const float* __restrict__ lin_l_b,
                                             const float* __restrict__ lin_r_w, const float* __restrict__ edge_w,
                                             float* __restrict__ pref, float* __restrict__ av, float* __restrict__ bv) {
    int i = blockIdx.x, t = threadIdx.x;   // block = 1 wave
    float pv = 0.f;
    if (t < P_DIM) {
        float s = lin_l_b[t];
        #pragma unroll
        for (int d = 0; d < D_EMB; ++d) {
            s += aggd[i * D_EMB + d] * lin_l_w[t * D_EMB + d];
            s += emb[i * D_EMB + d] * lin_r_w[t * D_EMB + d];
        }
        pref[i * P_DIM + t] = s;
        pv = s;
    }
    float a = (t < P_DIM) ? pv * edge_w[t] : 0.f;
    float b = (t < P_DIM) ? pv * edge_w[P_DIM + t] : 0.f;
    #pragma unroll
    for (int off = 32; off; off >>= 1) { a += __shfl_xor(a, off, 64); b += __shfl_xor(b, off, 64); }
    if (t == 0) { av[i] = a; bv[i] = b; }
}

// ---------------- per-column epilogue constants ----------------
__global__ void k_cvec(const float* __restrict__ comb_w, const float* __restrict__ comb_b,
                       const int* __restrict__ wk_p, const int* __restrict__ vh_p,
                       float* __restrict__ cvec, float* __restrict__ w3) {
    int j = blockIdx.x * 256 + threadIdx.x;
    float wk = (float)wk_p[0], vh = (float)vh_p[0];
    const float* wr = comb_w + (size_t)j * IN_LEN;
    cvec[j] = wk * wr[4128] + vh * wr[4129] + comb_b[j];
    w3[j] = wr[4130];
}

// ---------------- main bf16 GEMM: C[2048x2048] = [es|dist|pref|0] @ [cw32:4128|cw0:32|0]^T ----------------
// 64x128 tile, 512 blocks (2/CU, independent barriers). Register-prefetch pipeline,
// XOR-swizzled LDS (conflict-free b128). f32 -> bf16 at staging (RNA, 2 ops).
__global__ __launch_bounds__(256) void k_gemm(const float* __restrict__ dist, const float* __restrict__ comb_w,
                                              const float* __restrict__ pref,
                                              const float* __restrict__ av, const float* __restrict__ bv,
                                              const float* __restrict__ edge_b, float* __restrict__ Cout) {
    __shared__ __attribute__((aligned(16))) short As[64 * 64];    // 8 KB
    __shared__ __attribute__((aligned(16))) short Bs[128 * 64];   // 16 KB
    int t = threadIdx.x;
    int tileM = blockIdx.y * 64, tileN = blockIdx.x * 128;
    int lane = t & 63;
    int wid = t >> 6;
    int waveM = wid & 1, waveN = wid >> 1;        // wave covers 32 rows x 64 cols
    int l16 = lane & 15, quad = lane >> 4;

    f32x4 acc[2][4];
    #pragma unroll
    for (int a_ = 0; a_ < 2; ++a_)
        #pragma unroll
        for (int b_ = 0; b_ < 4; ++b_) acc[a_][b_] = (f32x4){0.f, 0.f, 0.f, 0.f};

    int ra = t >> 2, qa = t & 3;   // A staging: row 0..63, 16-col quarter
    int rb = t >> 1, hb = t & 1;   // B staging: row 0..127, 32-col half
    float a_base = av[tileM + ra] + edge_b[0];
    const float* distrow = dist + (size_t)(tileM + ra) * 2048 + qa * 16;
    const float* prefrow = pref + (size_t)(tileM + ra) * P_DIM + qa * 16;   // valid qa<2
    const float* browK = comb_w + (size_t)(tileN + rb) * IN_LEN + 32 + hb * 32;
    const float* brow0 = comb_w + (size_t)(tileN + rb) * IN_LEN;            // k0=4096, hb=0

    f32x4 pa[4], pb[8];

    auto loadA = [&](int k0) {
        if (k0 < 2048) {
            const f32x4* bp = (const f32x4*)&bv[k0 + qa * 16];
            #pragma unroll
            for (int u = 0; u < 4; ++u) pa[u] = bp[u];
        } else if (k0 < 4096) {
            const f32x4* sp = (const f32x4*)(distrow + (k0 - 2048));
            #pragma unroll
            for (int u = 0; u < 4; ++u) pa[u] = sp[u];
        } else {
            if (qa < 2) {
                const f32x4* sp = (const f32x4*)prefrow;
                #pragma unroll
                for (int u = 0; u < 4; ++u) pa[u] = sp[u];
            } else {
                #pragma unroll
                for (int u = 0; u < 4; ++u) pa[u] = (f32x4){0.f, 0.f, 0.f, 0.f};
            }
        }
    };
    auto loadB = [&](int k0) {
        if (k0 < 4096) {
            const float* src = browK + k0;                    // 4B-aligned
            #pragma unroll
            for (int u = 0; u < 8; ++u) __builtin_memcpy(&pb[u], src + u * 4, 16);
        } else {
            if (hb == 0) {
                #pragma unroll
                for (int u = 0; u < 8; ++u) __builtin_memcpy(&pb[u], brow0 + u * 4, 16);
            } else {
                #pragma unroll
                for (int u = 0; u < 8; ++u) pb[u] = (f32x4){0.f, 0.f, 0.f, 0.f};
            }
        }
    };
    auto storeAB = [&](int k0) {
        bool es = (k0 < 2048);
        #pragma unroll
        for (int u = 0; u < 2; ++u) {
            f32x4 f0 = pa[2 * u], f1 = pa[2 * u + 1];
            bf16x8 v;
            #pragma unroll
            for (int j = 0; j < 4; ++j) {
                float s0 = f0[j], s1 = f1[j];
                if (es) {
                    s0 += a_base; s0 = (s0 >= 0.f) ? s0 : 0.01f * s0;
                    s1 += a_base; s1 = (s1 >= 0.f) ? s1 : 0.01f * s1;
                }
                v[j] = (short)f2bf(s0);
                v[4 + j] = (short)f2bf(s1);
            }
            *(bf16x8*)&As[SWZ(ra, qa * 2 + u)] = v;
        }
        #pragma unroll
        for (int u = 0; u < 4; ++u) {
            f32x4 f0 = pb[2 * u], f1 = pb[2 * u + 1];
            bf16x8 v;
            #pragma unroll
            for (int j = 0; j < 4; ++j) { v[j] = (short)f2bf(f0[j]); v[4 + j] = (short)f2bf(f1[j]); }
            *(bf16x8*)&Bs[SWZ(rb, hb * 4 + u)] = v;
        }
    };

    loadA(0); loadB(0);
    for (int k0 = 0; k0 < KGEMM; k0 += 64) {
        __syncthreads();
        storeAB(k0);
        __syncthreads();
        if (k0 + 64 < KGEMM) { loadA(k0 + 64); loadB(k0 + 64); }
        #pragma unroll
        for (int kk = 0; kk < 64; kk += 32) {
            int cbase = kk >> 3;
            bf16x8 af[2], bfr[4];
            #pragma unroll
            for (int mi = 0; mi < 2; ++mi) {
                int row = waveM * 32 + mi * 16 + l16;
                af[mi] = *(const bf16x8*)&As[SWZ(row, cbase + quad)];
            }
            #pragma unroll
            for (int ni = 0; ni < 4; ++ni) {
                int row = waveN * 64 + ni * 16 + l16;
                bfr[ni] = *(const bf16x8*)&Bs[SWZ(row, cbase + quad)];
            }
            #pragma unroll
            for (int mi = 0; mi < 2; ++mi)
                #pragma unroll
                for (int ni = 0; ni < 4; ++ni)
                    acc[mi][ni] = __builtin_amdgcn_mfma_f32_16x16x32_bf16(af[mi], bfr[ni], acc[mi][ni], 0, 0, 0);
        }
    }
    #pragma unroll
    for (int mi = 0; mi < 2; ++mi)
        #pragma unroll
        for (int ni = 0; ni < 4; ++ni) {
            int row = tileM + waveM * 32 + mi * 16 + quad * 4;
            int col = tileN + waveN * 64 + ni * 16 + l16;
            float* cp = Cout + (size_t)row * N_NODES + col;
            #pragma unroll
            for (int rr = 0; rr < 4; ++rr) cp[(size_t)rr * N_NODES] = acc[mi][ni][rr];
        }
}

// ---------------- epilogue: + cvec + keep_i*w3, then log-softmax (in place, f32, coalesced) ----------------
__global__ __launch_bounds__(256) void k_epi(const float* __restrict__ cvec, const float* __restrict__ w3,
                                             const int* __restrict__ keep, float* __restrict__ out) {
    int i = blockIdx.x, t = threadIdx.x;
    __shared__ float redmax[4], redsum[4];
    float ki = keep[i] ? 1.f : 0.f;
    float vals[8];
    float vmax = -1e30f;
    #pragma unroll
    for (int u = 0; u < 8; ++u) {
        int j = t + u * 256;
        float v = out[(size_t)i * N_NODES + j] + cvec[j] + ki * w3[j];
        vals[u] = v;
        vmax = fmaxf(vmax, v);
    }
    #pragma unroll
    for (int off = 32; off; off >>= 1) vmax = fmaxf(vmax, __shfl_xor(vmax, off, 64));
    if ((t & 63) == 0) redmax[t >> 6] = vmax;
    __syncthreads();
    vmax = fmaxf(fmaxf(redmax[0], redmax[1]), fmaxf(redmax[2], redmax[3]));
    float se = 0.f;
    #pragma unroll
    for (int u = 0; u < 8; ++u) se += expf(vals[u] - vmax);
    #pragma unroll
    for (int off = 32; off; off >>= 1) se += __shfl_xor(se, off, 64);
    if ((t & 63) == 0) redsum[t >> 6] = se;
    __syncthreads();
    se = redsum[0] + redsum[1] + redsum[2] + redsum[3];
    float lz = vmax + logf(se);
    #pragma unroll
    for (int u = 0; u < 8; ++u) out[(size_t)i * N_NODES + t + u * 256] = vals[u] - lz;
}

extern "C" void kernel_launch(void* const* d_in, const int* in_sizes, int n_in,
                              void* d_out, int out_size, void* d_ws, size_t ws_size,
                              hipStream_t stream) {
    const float* dist    = (const float*)d_in[0];
    const float* emb     = (const float*)d_in[1];
    const float* lin_l_w = (const float*)d_in[2];
    const float* lin_l_b = (const float*)d_in[3];
    const float* lin_r_w = (const float*)d_in[4];
    const float* edge_w  = (const float*)d_in[5];
    const float* edge_b  = (const float*)d_in[6];
    const float* comb_w  = (const float*)d_in[7];
    const float* comb_b  = (const float*)d_in[8];
    const int* stops     = (const int*)d_in[9];
    const int* wk        = (const int*)d_in[10];
    const int* vh        = (const int*)d_in[11];

    // workspace: ~1.35 MB used
    char* ws = (char*)d_ws;
    float* xn    = (float*)(ws + 0);          // 524288
    int*   keep  = (int*)(ws + 524288);       // 8192
    float* aggd  = (float*)(ws + 532480);     // 524288
    float* pref  = (float*)(ws + 1056768);    // 262144
    float* av    = (float*)(ws + 1318912);    // 8192
    float* bv    = (float*)(ws + 1327104);    // 8192
    float* cvec  = (float*)(ws + 1335296);    // 8192
    float* w3    = (float*)(ws + 1343488);    // 8192
    float* out   = (float*)d_out;             // f32 [2048,2048]; holds C between k_gemm and k_epi

    hipLaunchKernelGGL(k_keep, dim3(8),      dim3(256), 0, stream, stops, keep);
    hipLaunchKernelGGL(k_xn,   dim3(512),    dim3(256), 0, stream, emb, xn);
    hipLaunchKernelGGL(k_agg,  dim3(2048),   dim3(256), 0, stream, xn, emb, keep, aggd);
    hipLaunchKernelGGL(k_pref, dim3(2048),   dim3(64),  0, stream, aggd, emb, lin_l_w, lin_l_b, lin_r_w, edge_w, pref, av, bv);
    hipLaunchKernelGGL(k_cvec, dim3(8),      dim3(256), 0, stream, comb_w, comb_b, wk, vh, cvec, w3);
    hipLaunchKernelGGL(k_gemm, dim3(16, 32), dim3(256), 0, stream, dist, comb_w, pref, av, bv, edge_b, out);
    hipLaunchKernelGGL(k_epi,  dim3(2048),   dim3(256), 0, stream, cvec, w3, keep, out);
}

// Round 9
// 253.685 us; speedup vs baseline: 1.9827x; 1.1784x over previous
//
#include <hip/hip_runtime.h>

typedef unsigned short u16;
typedef __attribute__((ext_vector_type(8))) short bf16x8;
typedef __attribute__((ext_vector_type(4))) float f32x4;

// round-to-nearest (ties away): 2 VALU ops
__device__ __forceinline__ u16 f2bf(float f) {
    return (u16)((__float_as_uint(f) + 0x8000u) >> 16);
}

#define N_NODES 2048
#define D_EMB 64
#define P_DIM 32
#define NS_STOPS 512
#define IN_LEN 4131   // 32 + 2048 + 2048 + 3
#define KGEMM 4160    // 2048 es + 2048 dist + 32 pref + 32 zero-pad
#define KPACK 4160

// 16B-chunk XOR swizzle: row has 8 chunks of 8 shorts
#define SWZ(row, c) ((((row) * 8) + ((c) ^ ((row) & 7))) * 8)

// ---------------- keep mask ----------------
__global__ void k_keep(const int* __restrict__ stops, int* __restrict__ keep) {
    __shared__ int s[NS_STOPS];
    int t = threadIdx.x;
    for (int u = t; u < NS_STOPS; u += 256) s[u] = stops[u];
    __syncthreads();
    int node = blockIdx.x * 256 + t;
    int f = 0;
    for (int u = 0; u < NS_STOPS; ++u) f |= (s[u] == node);
    keep[node] = f;
}

// ---------------- row-normalized embeddings (fp32) ----------------
__global__ void k_xn(const float* __restrict__ emb, float* __restrict__ xn) {
    int t = threadIdx.x;
    int row = blockIdx.x * 4 + (t >> 6);
    int d = t & 63;
    float v = emb[row * D_EMB + d];
    float s = v * v;
    #pragma unroll
    for (int off = 32; off; off >>= 1) s += __shfl_xor(s, off, 64);
    float nm = fmaxf(sqrtf(s), 1e-8f);
    xn[row * D_EMB + d] = v / nm;
}

// ---------------- cosine graph + mean aggregation ----------------
__global__ __launch_bounds__(256) void k_agg(const float* __restrict__ xn, const float* __restrict__ emb,
                                             const int* __restrict__ keep, float* __restrict__ aggd) {
    int i = blockIdx.x, t = threadIdx.x;
    __shared__ float xi[D_EMB];
    __shared__ float aggL[D_EMB];
    __shared__ int degL;
    int ki = keep[i];            // block-uniform
    if (t < D_EMB) { xi[t] = xn[i * D_EMB + t]; aggL[t] = 0.f; }
    if (t == 0) degL = 0;
    __syncthreads();
    if (ki) {
        for (int j = t; j < N_NODES; j += 256) {
            if (!keep[j] || j == i) continue;
            const float* xj = &xn[j * D_EMB];
            float dot = 0.f;
            #pragma unroll
            for (int d = 0; d < D_EMB; ++d) dot += xi[d] * xj[d];
            if (dot > 0.5f) {
                atomicAdd(&degL, 1);
                #pragma unroll
                for (int d = 0; d < D_EMB; ++d) atomicAdd(&aggL[d], emb[j * D_EMB + d]);
            }
        }
    }
    __syncthreads();
    if (t < D_EMB) {
        float deg = fmaxf((float)degL, 1.0f);
        aggd[i * D_EMB + t] = ki ? (aggL[t] / deg) : 0.f;
    }
}

// ---------------- pref + a,b vectors ----------------
__global__ __launch_bounds__(64) void k_pref(const float* __restrict__ aggd, const float* __restrict__ emb,
                                             const float* __restrict__ lin_l_w, const float* __restrict__ lin_l_b,
                                             const float* __restrict__ lin_r_w, const float* __restrict__ edge_w,
                                             float* __restrict__ pref, float* __restrict__ av, float* __restrict__ bv) {
    int i = blockIdx.x, t = threadIdx.x;   // block = 1 wave
    float pv = 0.f;
    if (t < P_DIM) {
        float s = lin_l_b[t];
        #pragma unroll
        for (int d = 0; d < D_EMB; ++d) {
            s += aggd[i * D_EMB + d] * lin_l_w[t * D_EMB + d];
            s += emb[i * D_EMB + d] * lin_r_w[t * D_EMB + d];
        }
        pref[i * P_DIM + t] = s;
        pv = s;
    }
    float a = (t < P_DIM) ? pv * edge_w[t] : 0.f;
    float b = (t < P_DIM) ? pv * edge_w[P_DIM + t] : 0.f;
    #pragma unroll
    for (int off = 32; off; off >>= 1) { a += __shfl_xor(a, off, 64); b += __shfl_xor(b, off, 64); }
    if (t == 0) { av[i] = a; bv[i] = b; }
}

// ---------------- per-column epilogue constants ----------------
__global__ void k_cvec(const float* __restrict__ comb_w, const float* __restrict__ comb_b,
                       const int* __restrict__ wk_p, const int* __restrict__ vh_p,
                       float* __restrict__ cvec, float* __restrict__ w3) {
    int j = blockIdx.x * 256 + threadIdx.x;
    float wk = (float)wk_p[0], vh = (float)vh_p[0];
    const float* wr = comb_w + (size_t)j * IN_LEN;
    cvec[j] = wk * wr[4128] + vh * wr[4129] + comb_b[j];
    w3[j] = wr[4130];
}

// ---------------- pack B: Bp[j][0:4096]=cw[j][32:4128], [4096:4128]=cw[j][0:32], [4128:4160]=0 ----------------
__global__ void k_pack_B(const float* __restrict__ comb_w, u16* __restrict__ Bp) {
    int j = blockIdx.x, t = threadIdx.x;
    const float* cw = comb_w + (size_t)j * IN_LEN;
    u16* dst = Bp + (size_t)j * KPACK;
    for (int c0 = t * 8; c0 < KPACK; c0 += 2048) {
        bf16x8 v;
        #pragma unroll
        for (int u = 0; u < 8; ++u) {
            int c = c0 + u;
            float val = (c < 4096) ? cw[32 + c] : ((c < 4128) ? cw[c - 4096] : 0.f);
            v[u] = (short)f2bf(val);
        }
        *(bf16x8*)&dst[c0] = v;
    }
}

// ---------------- pack dist -> bf16 ----------------
__global__ void k_pack_D(const float* __restrict__ dist, u16* __restrict__ Db) {
    int idx = blockIdx.x * 256 + threadIdx.x;
    int base = idx * 8;
    const f32x4* sp = (const f32x4*)(dist + base);
    f32x4 a = sp[0], b = sp[1];
    bf16x8 v;
    #pragma unroll
    for (int u = 0; u < 4; ++u) { v[u] = (short)f2bf(a[u]); v[4 + u] = (short)f2bf(b[u]); }
    *(bf16x8*)&Db[base] = v;
}

// ---------------- packed GEMM: C = [es|Db|prefpad] @ Bp^T ----------------
__global__ __launch_bounds__(256) void k_gemm_p(const u16* __restrict__ Db, const u16* __restrict__ Bp,
                                                const float* __restrict__ pref,
                                                const float* __restrict__ av, const float* __restrict__ bv,
                                                const float* __restrict__ edge_b, float* __restrict__ Cout) {
    __shared__ __attribute__((aligned(16))) short As[64 * 64];    // 8 KB
    __shared__ __attribute__((aligned(16))) short Bs[128 * 64];   // 16 KB
    int t = threadIdx.x;
    int tileM = blockIdx.y * 64, tileN = blockIdx.x * 128;
    int lane = t & 63;
    int wid = t >> 6;
    int waveM = wid & 1, waveN = wid >> 1;
    int l16 = lane & 15, quad = lane >> 4;

    f32x4 acc[2][4];
    #pragma unroll
    for (int a_ = 0; a_ < 2; ++a_)
        #pragma unroll
        for (int b_ = 0; b_ < 4; ++b_) acc[a_][b_] = (f32x4){0.f, 0.f, 0.f, 0.f};

    int ra = t >> 2, qa = t & 3;   // A: row 0..63, 16-col quarter
    int rb = t >> 1, hb = t & 1;   // B: row 0..127, 32-col half
    float a_base = av[tileM + ra] + edge_b[0];
    const u16* dbrow = Db + (size_t)(tileM + ra) * 2048 + qa * 16;
    const float* prefrow = pref + (size_t)(tileM + ra) * P_DIM + qa * 16;   // valid qa<2
    const u16* bprow = Bp + (size_t)(tileN + rb) * KPACK + hb * 32;

    f32x4 pa[4];      // es / pref f32 prefetch
    bf16x8 pav[2];    // dist bf16 prefetch
    bf16x8 pbv[4];    // B bf16 prefetch

    auto loadA = [&](int k0) {
        if (k0 < 2048) {
            const f32x4* bp = (const f32x4*)&bv[k0 + qa * 16];
            #pragma unroll
            for (int u = 0; u < 4; ++u) pa[u] = bp[u];
        } else if (k0 < 4096) {
            const bf16x8* sp = (const bf16x8*)(dbrow + (k0 - 2048));
            pav[0] = sp[0]; pav[1] = sp[1];
        } else {
            if (qa < 2) {
                const f32x4* sp = (const f32x4*)prefrow;
                #pragma unroll
                for (int u = 0; u < 4; ++u) pa[u] = sp[u];
            } else {
                #pragma unroll
                for (int u = 0; u < 4; ++u) pa[u] = (f32x4){0.f, 0.f, 0.f, 0.f};
            }
        }
    };
    auto loadB = [&](int k0) {
        const bf16x8* src = (const bf16x8*)(bprow + k0);
        #pragma unroll
        for (int u = 0; u < 4; ++u) pbv[u] = src[u];
    };
    auto storeAB = [&](int k0) {
        if (k0 >= 2048 && k0 < 4096) {
            *(bf16x8*)&As[SWZ(ra, qa * 2 + 0)] = pav[0];
            *(bf16x8*)&As[SWZ(ra, qa * 2 + 1)] = pav[1];
        } else {
            bool es = (k0 < 2048);
            #pragma unroll
            for (int u = 0; u < 2; ++u) {
                f32x4 f0 = pa[2 * u], f1 = pa[2 * u + 1];
                bf16x8 v;
                #pragma unroll
                for (int j = 0; j < 4; ++j) {
                    float s0 = f0[j], s1 = f1[j];
                    if (es) {
                        s0 += a_base; s0 = (s0 >= 0.f) ? s0 : 0.01f * s0;
                        s1 += a_base; s1 = (s1 >= 0.f) ? s1 : 0.01f * s1;
                    }
                    v[j] = (short)f2bf(s0);
                    v[4 + j] = (short)f2bf(s1);
                }
                *(bf16x8*)&As[SWZ(ra, qa * 2 + u)] = v;
            }
        }
        #pragma unroll
        for (int u = 0; u < 4; ++u)
            *(bf16x8*)&Bs[SWZ(rb, hb * 4 + u)] = pbv[u];
    };

    loadA(0); loadB(0);
    for (int k0 = 0; k0 < KGEMM; k0 += 64) {
        __syncthreads();
        storeAB(k0);
        __syncthreads();
        if (k0 + 64 < KGEMM) { loadA(k0 + 64); loadB(k0 + 64); }
        #pragma unroll
        for (int kk = 0; kk < 64; kk += 32) {
            int cbase = kk >> 3;
            bf16x8 af[2], bfr[4];
            #pragma unroll
            for (int mi = 0; mi < 2; ++mi) {
                int row = waveM * 32 + mi * 16 + l16;
                af[mi] = *(const bf16x8*)&As[SWZ(row, cbase + quad)];
            }
            #pragma unroll
            for (int ni = 0; ni < 4; ++ni) {
                int row = waveN * 64 + ni * 16 + l16;
                bfr[ni] = *(const bf16x8*)&Bs[SWZ(row, cbase + quad)];
            }
            #pragma unroll
            for (int mi = 0; mi < 2; ++mi)
                #pragma unroll
                for (int ni = 0; ni < 4; ++ni)
                    acc[mi][ni] = __builtin_amdgcn_mfma_f32_16x16x32_bf16(af[mi], bfr[ni], acc[mi][ni], 0, 0, 0);
        }
    }
    #pragma unroll
    for (int mi = 0; mi < 2; ++mi)
        #pragma unroll
        for (int ni = 0; ni < 4; ++ni) {
            int row = tileM + waveM * 32 + mi * 16 + quad * 4;
            int col = tileN + waveN * 64 + ni * 16 + l16;
            float* cp = Cout + (size_t)row * N_NODES + col;
            #pragma unroll
            for (int rr = 0; rr < 4; ++rr) cp[(size_t)rr * N_NODES] = acc[mi][ni][rr];
        }
}

// ---------------- fallback GEMM (round-8 path, comb_w/dist read directly) ----------------
__global__ __launch_bounds__(256) void k_gemm(const float* __restrict__ dist, const float* __restrict__ comb_w,
                                              const float* __restrict__ pref,
                                              const float* __restrict__ av, const float* __restrict__ bv,
                                              const float* __restrict__ edge_b, float* __restrict__ Cout) {
    __shared__ __attribute__((aligned(16))) short As[64 * 64];
    __shared__ __attribute__((aligned(16))) short Bs[128 * 64];
    int t = threadIdx.x;
    int tileM = blockIdx.y * 64, tileN = blockIdx.x * 128;
    int lane = t & 63;
    int wid = t >> 6;
    int waveM = wid & 1, waveN = wid >> 1;
    int l16 = lane & 15, quad = lane >> 4;

    f32x4 acc[2][4];
    #pragma unroll
    for (int a_ = 0; a_ < 2; ++a_)
        #pragma unroll
        for (int b_ = 0; b_ < 4; ++b_) acc[a_][b_] = (f32x4){0.f, 0.f, 0.f, 0.f};

    int ra = t >> 2, qa = t & 3;
    int rb = t >> 1, hb = t & 1;
    float a_base = av[tileM + ra] + edge_b[0];
    const float* distrow = dist + (size_t)(tileM + ra) * 2048 + qa * 16;
    const float* prefrow = pref + (size_t)(tileM + ra) * P_DIM + qa * 16;
    const float* browK = comb_w + (size_t)(tileN + rb) * IN_LEN + 32 + hb * 32;
    const float* brow0 = comb_w + (size_t)(tileN + rb) * IN_LEN;

    f32x4 pa[4], pb[8];

    auto loadA = [&](int k0) {
        if (k0 < 2048) {
            const f32x4* bp = (const f32x4*)&bv[k0 + qa * 16];
            #pragma unroll
            for (int u = 0; u < 4; ++u) pa[u] = bp[u];
        } else if (k0 < 4096) {
            const f32x4* sp = (const f32x4*)(distrow + (k0 - 2048));
            #pragma unroll
            for (int u = 0; u < 4; ++u) pa[u] = sp[u];
        } else {
            if (qa < 2) {
                const f32x4* sp = (const f32x4*)prefrow;
                #pragma unroll
                for (int u = 0; u < 4; ++u) pa[u] = sp[u];
            } else {
                #pragma unroll
                for (int u = 0; u < 4; ++u) pa[u] = (f32x4){0.f, 0.f, 0.f, 0.f};
            }
        }
    };
    auto loadB = [&](int k0) {
        if (k0 < 4096) {
            const float* src = browK + k0;
            #pragma unroll
            for (int u = 0; u < 8; ++u) __builtin_memcpy(&pb[u], src + u * 4, 16);
        } else {
            if (hb == 0) {
                #pragma unroll
                for (int u = 0; u < 8; ++u) __builtin_memcpy(&pb[u], brow0 + u * 4, 16);
            } else {
                #pragma unroll
                for (int u = 0; u < 8; ++u) pb[u] = (f32x4){0.f, 0.f, 0.f, 0.f};
            }
        }
    };
    auto storeAB = [&](int k0) {
        bool es = (k0 < 2048);
        #pragma unroll
        for (int u = 0; u < 2; ++u) {
            f32x4 f0 = pa[2 * u], f1 = pa[2 * u + 1];
            bf16x8 v;
            #pragma unroll
            for (int j = 0; j < 4; ++j) {
                float s0 = f0[j], s1 = f1[j];
                if (es) {
                    s0 += a_base; s0 = (s0 >= 0.f) ? s0 : 0.01f * s0;
                    s1 += a_base; s1 = (s1 >= 0.f) ? s1 : 0.01f * s1;
                }
                v[j] = (short)f2bf(s0);
                v[4 + j] = (short)f2bf(s1);
            }
            *(bf16x8*)&As[SWZ(ra, qa * 2 + u)] = v;
        }
        #pragma unroll
        for (int u = 0; u < 4; ++u) {
            f32x4 f0 = pb[2 * u], f1 = pb[2 * u + 1];
            bf16x8 v;
            #pragma unroll
            for (int j = 0; j < 4; ++j) { v[j] = (short)f2bf(f0[j]); v[4 + j] = (short)f2bf(f1[j]); }
            *(bf16x8*)&Bs[SWZ(rb, hb * 4 + u)] = v;
        }
    };

    loadA(0); loadB(0);
    for (int k0 = 0; k0 < KGEMM; k0 += 64) {
        __syncthreads();
        storeAB(k0);
        __syncthreads();
        if (k0 + 64 < KGEMM) { loadA(k0 + 64); loadB(k0 + 64); }
        #pragma unroll
        for (int kk = 0; kk < 64; kk += 32) {
            int cbase = kk >> 3;
            bf16x8 af[2], bfr[4];
            #pragma unroll
            for (int mi = 0; mi < 2; ++mi) {
                int row = waveM * 32 + mi * 16 + l16;
                af[mi] = *(const bf16x8*)&As[SWZ(row, cbase + quad)];
            }
            #pragma unroll
            for (int ni = 0; ni < 4; ++ni) {
                int row = waveN * 64 + ni * 16 + l16;
                bfr[ni] = *(const bf16x8*)&Bs[SWZ(row, cbase + quad)];
            }
            #pragma unroll
            for (int mi = 0; mi < 2; ++mi)
                #pragma unroll
                for (int ni = 0; ni < 4; ++ni)
                    acc[mi][ni] = __builtin_amdgcn_mfma_f32_16x16x32_bf16(af[mi], bfr[ni], acc[mi][ni], 0, 0, 0);
        }
    }
    #pragma unroll
    for (int mi = 0; mi < 2; ++mi)
        #pragma unroll
        for (int ni = 0; ni < 4; ++ni) {
            int row = tileM + waveM * 32 + mi * 16 + quad * 4;
            int col = tileN + waveN * 64 + ni * 16 + l16;
            float* cp = Cout + (size_t)row * N_NODES + col;
            #pragma unroll
            for (int rr = 0; rr < 4; ++rr) cp[(size_t)rr * N_NODES] = acc[mi][ni][rr];
        }
}

// ---------------- epilogue: + cvec + keep_i*w3, then log-softmax (in place, f32, coalesced) ----------------
__global__ __launch_bounds__(256) void k_epi(const float* __restrict__ cvec, const float* __restrict__ w3,
                                             const int* __restrict__ keep, float* __restrict__ out) {
    int i = blockIdx.x, t = threadIdx.x;
    __shared__ float redmax[4], redsum[4];
    float ki = keep[i] ? 1.f : 0.f;
    float vals[8];
    float vmax = -1e30f;
    #pragma unroll
    for (int u = 0; u < 8; ++u) {
        int j = t + u * 256;
        float v = out[(size_t)i * N_NODES + j] + cvec[j] + ki * w3[j];
        vals[u] = v;
        vmax = fmaxf(vmax, v);
    }
    #pragma unroll
    for (int off = 32; off; off >>= 1) vmax = fmaxf(vmax, __shfl_xor(vmax, off, 64));
    if ((t & 63) == 0) redmax[t >> 6] = vmax;
    __syncthreads();
    vmax = fmaxf(fmaxf(redmax[0], redmax[1]), fmaxf(redmax[2], redmax[3]));
    float se = 0.f;
    #pragma unroll
    for (int u = 0; u < 8; ++u) se += expf(vals[u] - vmax);
    #pragma unroll
    for (int off = 32; off; off >>= 1) se += __shfl_xor(se, off, 64);
    if ((t & 63) == 0) redsum[t >> 6] = se;
    __syncthreads();
    se = redsum[0] + redsum[1] + redsum[2] + redsum[3];
    float lz = vmax + logf(se);
    #pragma unroll
    for (int u = 0; u < 8; ++u) out[(size_t)i * N_NODES + t + u * 256] = vals[u] - lz;
}

extern "C" void kernel_launch(void* const* d_in, const int* in_sizes, int n_in,
                              void* d_out, int out_size, void* d_ws, size_t ws_size,
                              hipStream_t stream) {
    const float* dist    = (const float*)d_in[0];
    const float* emb     = (const float*)d_in[1];
    const float* lin_l_w = (const float*)d_in[2];
    const float* lin_l_b = (const float*)d_in[3];
    const float* lin_r_w = (const float*)d_in[4];
    const float* edge_w  = (const float*)d_in[5];
    const float* edge_b  = (const float*)d_in[6];
    const float* comb_w  = (const float*)d_in[7];
    const float* comb_b  = (const float*)d_in[8];
    const int* stops     = (const int*)d_in[9];
    const int* wk        = (const int*)d_in[10];
    const int* vh        = (const int*)d_in[11];

    char* ws = (char*)d_ws;
    float* xn    = (float*)(ws + 0);          // 524288
    int*   keep  = (int*)(ws + 524288);       // 8192
    float* aggd  = (float*)(ws + 532480);     // 524288
    float* pref  = (float*)(ws + 1056768);    // 262144
    float* av    = (float*)(ws + 1318912);    // 8192
    float* bv    = (float*)(ws + 1327104);    // 8192
    float* cvec  = (float*)(ws + 1335296);    // 8192
    float* w3    = (float*)(ws + 1343488);    // 8192
    u16*   Bp    = (u16*)(ws + 1351680);      // 2048*4160*2 = 17039360
    u16*   Db    = (u16*)(ws + 18391040);     // 2048*2048*2 = 8388608 -> end 26779648
    float* out   = (float*)d_out;             // f32 [2048,2048]; holds C between gemm and epi

    const size_t need_packed = 26779648;

    hipLaunchKernelGGL(k_keep, dim3(8),    dim3(256), 0, stream, stops, keep);
    hipLaunchKernelGGL(k_xn,   dim3(512),  dim3(256), 0, stream, emb, xn);
    hipLaunchKernelGGL(k_agg,  dim3(2048), dim3(256), 0, stream, xn, emb, keep, aggd);
    hipLaunchKernelGGL(k_pref, dim3(2048), dim3(64),  0, stream, aggd, emb, lin_l_w, lin_l_b, lin_r_w, edge_w, pref, av, bv);
    hipLaunchKernelGGL(k_cvec, dim3(8),    dim3(256), 0, stream, comb_w, comb_b, wk, vh, cvec, w3);

    if (ws_size >= need_packed) {
        hipLaunchKernelGGL(k_pack_B, dim3(2048),   dim3(256), 0, stream, comb_w, Bp);
        hipLaunchKernelGGL(k_pack_D, dim3(2048),   dim3(256), 0, stream, dist, Db);
        hipLaunchKernelGGL(k_gemm_p, dim3(16, 32), dim3(256), 0, stream, Db, Bp, pref, av, bv, edge_b, out);
    } else {
        hipLaunchKernelGGL(k_gemm,   dim3(16, 32), dim3(256), 0, stream, dist, comb_w, pref, av, bv, edge_b, out);
    }
    hipLaunchKernelGGL(k_epi, dim3(2048), dim3(256), 0, stream, cvec, w3, keep, out);
}

// Round 10
// 240.672 us; speedup vs baseline: 2.0899x; 1.0541x over previous
//
#include <hip/hip_runtime.h>

typedef unsigned short u16;
typedef __attribute__((ext_vector_type(8))) short bf16x8;
typedef __attribute__((ext_vector_type(4))) float f32x4;

// round-to-nearest (ties away): 2 VALU ops
__device__ __forceinline__ u16 f2bf(float f) {
    return (u16)((__float_as_uint(f) + 0x8000u) >> 16);
}

#define N_NODES 2048
#define D_EMB 64
#define P_DIM 32
#define NS_STOPS 512
#define IN_LEN 4131   // 32 + 2048 + 2048 + 3
#define KGEMM 4160    // 2048 es + 2048 dist + 32 pref + 32 zero-pad
#define KPACK 4160
#define NKT 65        // K-tiles of 64

// 16B-chunk XOR swizzle: row has 8 chunks of 8 shorts
#define SWZ(row, c) ((((row) * 8) + ((c) ^ ((row) & 7))) * 8)

__device__ __forceinline__ void gload16(const u16* g, u16* l) {
    __builtin_amdgcn_global_load_lds((const __attribute__((address_space(1))) void*)g,
                                     (__attribute__((address_space(3))) void*)l, 16, 0, 0);
}

// ---------------- keep mask + compact list (single block) ----------------
__global__ __launch_bounds__(1024) void k_keep(const int* __restrict__ stops, int* __restrict__ keep,
                                               int* __restrict__ klist, int* __restrict__ knum) {
    __shared__ int s[NS_STOPS];
    __shared__ int cnt;
    int t = threadIdx.x;
    if (t < NS_STOPS) s[t] = stops[t];
    if (t == 0) cnt = 0;
    __syncthreads();
    for (int n = t; n < N_NODES; n += 1024) {
        int f = 0;
        for (int u = 0; u < NS_STOPS; ++u) f |= (s[u] == n);
        keep[n] = f;
        if (f) { int p = atomicAdd(&cnt, 1); klist[p] = n; }
    }
    __syncthreads();
    if (t == 0) *knum = cnt;
}

// ---------------- row-normalized embeddings (fp32) ----------------
__global__ void k_xn(const float* __restrict__ emb, float* __restrict__ xn) {
    int t = threadIdx.x;
    int row = blockIdx.x * 4 + (t >> 6);
    int d = t & 63;
    float v = emb[row * D_EMB + d];
    float s = v * v;
    #pragma unroll
    for (int off = 32; off; off >>= 1) s += __shfl_xor(s, off, 64);
    float nm = fmaxf(sqrtf(s), 1e-8f);
    xn[row * D_EMB + d] = v / nm;
}

// ---------------- cosine graph + mean aggregation (compact list) ----------------
__global__ __launch_bounds__(256) void k_agg_list(const float* __restrict__ xn, const float* __restrict__ emb,
                                                  const int* __restrict__ keep, const int* __restrict__ klist,
                                                  const int* __restrict__ knum, float* __restrict__ aggd) {
    int i = blockIdx.x, t = threadIdx.x;
    __shared__ float xi[D_EMB];
    __shared__ float aggL[D_EMB];
    __shared__ int degL;
    int ki = keep[i];            // block-uniform
    if (t < D_EMB) { xi[t] = xn[i * D_EMB + t]; aggL[t] = 0.f; }
    if (t == 0) degL = 0;
    __syncthreads();
    if (ki) {
        int nk = knum[0];
        const f32x4* xiv = (const f32x4*)xi;
        for (int u = t; u < nk; u += 256) {
            int j = klist[u];
            if (j == i) continue;
            const f32x4* xj = (const f32x4*)&xn[j * D_EMB];
            f32x4 dv = {0.f, 0.f, 0.f, 0.f};
            #pragma unroll
            for (int d = 0; d < 16; ++d) dv += xiv[d] * xj[d];
            float dot = dv[0] + dv[1] + dv[2] + dv[3];
            if (dot > 0.5f) {
                atomicAdd(&degL, 1);
                #pragma unroll
                for (int d = 0; d < D_EMB; ++d) atomicAdd(&aggL[d], emb[j * D_EMB + d]);
            }
        }
    }
    __syncthreads();
    if (t < D_EMB) {
        float deg = fmaxf((float)degL, 1.0f);
        aggd[i * D_EMB + t] = ki ? (aggL[t] / deg) : 0.f;
    }
}

// ---------------- fallback agg (full scan, round-9) ----------------
__global__ __launch_bounds__(256) void k_agg_scan(const float* __restrict__ xn, const float* __restrict__ emb,
                                                  const int* __restrict__ keep, float* __restrict__ aggd) {
    int i = blockIdx.x, t = threadIdx.x;
    __shared__ float xi[D_EMB];
    __shared__ float aggL[D_EMB];
    __shared__ int degL;
    int ki = keep[i];
    if (t < D_EMB) { xi[t] = xn[i * D_EMB + t]; aggL[t] = 0.f; }
    if (t == 0) degL = 0;
    __syncthreads();
    if (ki) {
        for (int j = t; j < N_NODES; j += 256) {
            if (!keep[j] || j == i) continue;
            const float* xj = &xn[j * D_EMB];
            float dot = 0.f;
            #pragma unroll
            for (int d = 0; d < D_EMB; ++d) dot += xi[d] * xj[d];
            if (dot > 0.5f) {
                atomicAdd(&degL, 1);
                #pragma unroll
                for (int d = 0; d < D_EMB; ++d) atomicAdd(&aggL[d], emb[j * D_EMB + d]);
            }
        }
    }
    __syncthreads();
    if (t < D_EMB) {
        float deg = fmaxf((float)degL, 1.0f);
        aggd[i * D_EMB + t] = ki ? (aggL[t] / deg) : 0.f;
    }
}

// ---------------- pref + a,b vectors (8 rows/block, f32x4 dots) ----------------
__global__ __launch_bounds__(256) void k_pref(const float* __restrict__ aggd, const float* __restrict__ emb,
                                              const float* __restrict__ lin_l_w, const float* __restrict__ lin_l_b,
                                              const float* __restrict__ lin_r_w, const float* __restrict__ edge_w,
                                              float* __restrict__ pref, float* __restrict__ av, float* __restrict__ bv) {
    int t = threadIdx.x;
    int i = blockIdx.x * 8 + (t >> 5);
    int p = t & 31;
    const f32x4* ar = (const f32x4*)&aggd[i * D_EMB];
    const f32x4* er = (const f32x4*)&emb[i * D_EMB];
    const f32x4* wl = (const f32x4*)&lin_l_w[p * D_EMB];
    const f32x4* wrr = (const f32x4*)&lin_r_w[p * D_EMB];
    f32x4 sv = {0.f, 0.f, 0.f, 0.f};
    #pragma unroll
    for (int d = 0; d < 16; ++d) sv += ar[d] * wl[d] + er[d] * wrr[d];
    float s = sv[0] + sv[1] + sv[2] + sv[3] + lin_l_b[p];
    pref[i * P_DIM + p] = s;
    float a = s * edge_w[p];
    float b = s * edge_w[P_DIM + p];
    #pragma unroll
    for (int off = 16; off; off >>= 1) { a += __shfl_xor(a, off, 64); b += __shfl_xor(b, off, 64); }
    if (p == 0) { av[i] = a; bv[i] = b; }
}

// ---------------- per-column epilogue constants ----------------
__global__ void k_cvec(const float* __restrict__ comb_w, const float* __restrict__ comb_b,
                       const int* __restrict__ wk_p, const int* __restrict__ vh_p,
                       float* __restrict__ cvec, float* __restrict__ w3) {
    int j = blockIdx.x * 256 + threadIdx.x;
    float wk = (float)wk_p[0], vh = (float)vh_p[0];
    const float* wr = comb_w + (size_t)j * IN_LEN;
    cvec[j] = wk * wr[4128] + vh * wr[4129] + comb_b[j];
    w3[j] = wr[4130];
}

// ---------------- pack A tiled+pre-swizzled: At[rt][kt][r][c^(r&7)] ----------------
__global__ void k_pack_At(const float* __restrict__ dist, const float* __restrict__ pref,
                          const float* __restrict__ av, const float* __restrict__ bv,
                          const float* __restrict__ edge_b, u16* __restrict__ Ap) {
    int row = blockIdx.x, t = threadIdx.x;
    int rt = row >> 6, r = row & 63;
    float ab = av[row] + edge_b[0];
    const float* drow = dist + (size_t)row * 2048;
    const float* prow = pref + (size_t)row * P_DIM;
    for (int q = t; q < 520; q += 256) {
        int kt = q >> 3, c = q & 7;
        int k0 = q * 8;
        bf16x8 v;
        #pragma unroll
        for (int e = 0; e < 8; ++e) {
            int k = k0 + e;
            float val;
            if (k < 2048) { val = ab + bv[k]; val = (val >= 0.f) ? val : 0.01f * val; }
            else if (k < 4096) val = drow[k - 2048];
            else if (k < 4128) val = prow[k - 4096];
            else val = 0.f;
            v[e] = (short)f2bf(val);
        }
        size_t off = (((size_t)rt * NKT + kt) * 64 + r) * 64 + (size_t)((c ^ (r & 7)) * 8);
        *(bf16x8*)&Ap[off] = v;
    }
}

// ---------------- pack B tiled+pre-swizzled: Bt[nt][kt][r(128)][c^(r&7)] ----------------
__global__ void k_pack_Bt(const float* __restrict__ comb_w, u16* __restrict__ Bp) {
    int j = blockIdx.x, t = threadIdx.x;
    int nt = j >> 7, r = j & 127;
    const float* cw = comb_w + (size_t)j * IN_LEN;
    for (int q = t; q < 520; q += 256) {
        int kt = q >> 3, c = q & 7;
        int k0 = q * 8;
        bf16x8 v;
        if (k0 < 4096) {
            float tmp[8];
            __builtin_memcpy(tmp, cw + 32 + k0, 32);
            #pragma unroll
            for (int e = 0; e < 8; ++e) v[e] = (short)f2bf(tmp[e]);
        } else if (k0 < 4128) {
            float tmp[8];
            __builtin_memcpy(tmp, cw + (k0 - 4096), 32);
            #pragma unroll
            for (int e = 0; e < 8; ++e) v[e] = (short)f2bf(tmp[e]);
        } else {
            #pragma unroll
            for (int e = 0; e < 8; ++e) v[e] = 0;
        }
        size_t off = (((size_t)nt * NKT + kt) * 128 + r) * 64 + (size_t)((c ^ (r & 7)) * 8);
        *(bf16x8*)&Bp[off] = v;
    }
}

// ---------------- tiled GEMM: global_load_lds DMA staging, zero staging VALU ----------------
__global__ __launch_bounds__(256) void k_gemm_t(const u16* __restrict__ Ap, const u16* __restrict__ Bp,
                                                float* __restrict__ Cout) {
    __shared__ __attribute__((aligned(16))) short As[64 * 64];    // 8 KB
    __shared__ __attribute__((aligned(16))) short Bs[128 * 64];   // 16 KB
    int t = threadIdx.x;
    int tileM = blockIdx.y * 64, tileN = blockIdx.x * 128;
    int lane = t & 63;
    int wid = t >> 6;
    int waveM = wid & 1, waveN = wid >> 1;
    int l16 = lane & 15, quad = lane >> 4;

    f32x4 acc[2][4];
    #pragma unroll
    for (int a_ = 0; a_ < 2; ++a_)
        #pragma unroll
        for (int b_ = 0; b_ < 4; ++b_) acc[a_][b_] = (f32x4){0.f, 0.f, 0.f, 0.f};

    const u16* aBase = Ap + ((size_t)blockIdx.y * NKT) * 4096 + t * 8;
    const u16* bBase = Bp + ((size_t)blockIdx.x * NKT) * 8192 + t * 8;
    u16* asDst = (u16*)As + t * 8;
    u16* bsDst = (u16*)Bs + t * 8;

    for (int kt = 0; kt < NKT; ++kt) {
        __syncthreads();
        const u16* ga = aBase + kt * 4096;
        const u16* gb = bBase + kt * 8192;
        gload16(ga, asDst);
        gload16(ga + 2048, asDst + 2048);
        #pragma unroll
        for (int u = 0; u < 4; ++u)
            gload16(gb + u * 2048, bsDst + u * 2048);
        __syncthreads();   // compiler emits s_waitcnt vmcnt(0) before barrier
        #pragma unroll
        for (int kk = 0; kk < 64; kk += 32) {
            int cbase = kk >> 3;
            bf16x8 af[2], bfr[4];
            #pragma unroll
            for (int mi = 0; mi < 2; ++mi) {
                int row = waveM * 32 + mi * 16 + l16;
                af[mi] = *(const bf16x8*)&As[SWZ(row, cbase + quad)];
            }
            #pragma unroll
            for (int ni = 0; ni < 4; ++ni) {
                int row = waveN * 64 + ni * 16 + l16;
                bfr[ni] = *(const bf16x8*)&Bs[SWZ(row, cbase + quad)];
            }
            #pragma unroll
            for (int mi = 0; mi < 2; ++mi)
                #pragma unroll
                for (int ni = 0; ni < 4; ++ni)
                    acc[mi][ni] = __builtin_amdgcn_mfma_f32_16x16x32_bf16(af[mi], bfr[ni], acc[mi][ni], 0, 0, 0);
        }
    }
    #pragma unroll
    for (int mi = 0; mi < 2; ++mi)
        #pragma unroll
        for (int ni = 0; ni < 4; ++ni) {
            int row = tileM + waveM * 32 + mi * 16 + quad * 4;
            int col = tileN + waveN * 64 + ni * 16 + l16;
            float* cp = Cout + (size_t)row * N_NODES + col;
            #pragma unroll
            for (int rr = 0; rr < 4; ++rr) cp[(size_t)rr * N_NODES] = acc[mi][ni][rr];
        }
}

// ================= fallback path (round-9, confirmed ws budget) =================
__global__ void k_pack_B(const float* __restrict__ comb_w, u16* __restrict__ Bp) {
    int j = blockIdx.x, t = threadIdx.x;
    const float* cw = comb_w + (size_t)j * IN_LEN;
    u16* dst = Bp + (size_t)j * KPACK;
    for (int c0 = t * 8; c0 < KPACK; c0 += 2048) {
        bf16x8 v;
        #pragma unroll
        for (int u = 0; u < 8; ++u) {
            int c = c0 + u;
            float val = (c < 4096) ? cw[32 + c] : ((c < 4128) ? cw[c - 4096] : 0.f);
            v[u] = (short)f2bf(val);
        }
        *(bf16x8*)&dst[c0] = v;
    }
}

__global__ void k_pack_D(const float* __restrict__ dist, u16* __restrict__ Db) {
    int idx = blockIdx.x * 256 + threadIdx.x;
    int base = idx * 8;
    const f32x4* sp = (const f32x4*)(dist + base);
    f32x4 a = sp[0], b = sp[1];
    bf16x8 v;
    #pragma unroll
    for (int u = 0; u < 4; ++u) { v[u] = (short)f2bf(a[u]); v[4 + u] = (short)f2bf(b[u]); }
    *(bf16x8*)&Db[base] = v;
}

__global__ __launch_bounds__(256) void k_gemm_p(const u16* __restrict__ Db, const u16* __restrict__ Bp,
                                                const float* __restrict__ pref,
                                                const float* __restrict__ av, const float* __restrict__ bv,
                                                const float* __restrict__ edge_b, float* __restrict__ Cout) {
    __shared__ __attribute__((aligned(16))) short As[64 * 64];
    __shared__ __attribute__((aligned(16))) short Bs[128 * 64];
    int t = threadIdx.x;
    int tileM = blockIdx.y * 64, tileN = blockIdx.x * 128;
    int lane = t & 63;
    int wid = t >> 6;
    int waveM = wid & 1, waveN = wid >> 1;
    int l16 = lane & 15, quad = lane >> 4;

    f32x4 acc[2][4];
    #pragma unroll
    for (int a_ = 0; a_ < 2; ++a_)
        #pragma unroll
        for (int b_ = 0; b_ < 4; ++b_) acc[a_][b_] = (f32x4){0.f, 0.f, 0.f, 0.f};

    int ra = t >> 2, qa = t & 3;
    int rb = t >> 1, hb = t & 1;
    float a_base = av[tileM + ra] + edge_b[0];
    const u16* dbrow = Db + (size_t)(tileM + ra) * 2048 + qa * 16;
    const float* prefrow = pref + (size_t)(tileM + ra) * P_DIM + qa * 16;
    const u16* bprow = Bp + (size_t)(tileN + rb) * KPACK + hb * 32;

    f32x4 pa[4];
    bf16x8 pav[2];
    bf16x8 pbv[4];

    auto loadA = [&](int k0) {
        if (k0 < 2048) {
            const f32x4* bp = (const f32x4*)&bv[k0 + qa * 16];
            #pragma unroll
            for (int u = 0; u < 4; ++u) pa[u] = bp[u];
        } else if (k0 < 4096) {
            const bf16x8* sp = (const bf16x8*)(dbrow + (k0 - 2048));
            pav[0] = sp[0]; pav[1] = sp[1];
        } else {
            if (qa < 2) {
                const f32x4* sp = (const f32x4*)prefrow;
                #pragma unroll
                for (int u = 0; u < 4; ++u) pa[u] = sp[u];
            } else {
                #pragma unroll
                for (int u = 0; u < 4; ++u) pa[u] = (f32x4){0.f, 0.f, 0.f, 0.f};
            }
        }
    };
    auto loadB = [&](int k0) {
        const bf16x8* src = (const bf16x8*)(bprow + k0);
        #pragma unroll
        for (int u = 0; u < 4; ++u) pbv[u] = src[u];
    };
    auto storeAB = [&](int k0) {
        if (k0 >= 2048 && k0 < 4096) {
            *(bf16x8*)&As[SWZ(ra, qa * 2 + 0)] = pav[0];
            *(bf16x8*)&As[SWZ(ra, qa * 2 + 1)] = pav[1];
        } else {
            bool es = (k0 < 2048);
            #pragma unroll
            for (int u = 0; u < 2; ++u) {
                f32x4 f0 = pa[2 * u], f1 = pa[2 * u + 1];
                bf16x8 v;
                #pragma unroll
                for (int j = 0; j < 4; ++j) {
                    float s0 = f0[j], s1 = f1[j];
                    if (es) {
                        s0 += a_base; s0 = (s0 >= 0.f) ? s0 : 0.01f * s0;
                        s1 += a_base; s1 = (s1 >= 0.f) ? s1 : 0.01f * s1;
                    }
                    v[j] = (short)f2bf(s0);
                    v[4 + j] = (short)f2bf(s1);
                }
                *(bf16x8*)&As[SWZ(ra, qa * 2 + u)] = v;
            }
        }
        #pragma unroll
        for (int u = 0; u < 4; ++u)
            *(bf16x8*)&Bs[SWZ(rb, hb * 4 + u)] = pbv[u];
    };

    loadA(0); loadB(0);
    for (int k0 = 0; k0 < KGEMM; k0 += 64) {
        __syncthreads();
        storeAB(k0);
        __syncthreads();
        if (k0 + 64 < KGEMM) { loadA(k0 + 64); loadB(k0 + 64); }
        #pragma unroll
        for (int kk = 0; kk < 64; kk += 32) {
            int cbase = kk >> 3;
            bf16x8 af[2], bfr[4];
            #pragma unroll
            for (int mi = 0; mi < 2; ++mi) {
                int row = waveM * 32 + mi * 16 + l16;
                af[mi] = *(const bf16x8*)&As[SWZ(row, cbase + quad)];
            }
            #pragma unroll
            for (int ni = 0; ni < 4; ++ni) {
                int row = waveN * 64 + ni * 16 + l16;
                bfr[ni] = *(const bf16x8*)&Bs[SWZ(row, cbase + quad)];
            }
            #pragma unroll
            for (int mi = 0; mi < 2; ++mi)
                #pragma unroll
                for (int ni = 0; ni < 4; ++ni)
                    acc[mi][ni] = __builtin_amdgcn_mfma_f32_16x16x32_bf16(af[mi], bfr[ni], acc[mi][ni], 0, 0, 0);
        }
    }
    #pragma unroll
    for (int mi = 0; mi < 2; ++mi)
        #pragma unroll
        for (int ni = 0; ni < 4; ++ni) {
            int row = tileM + waveM * 32 + mi * 16 + quad * 4;
            int col = tileN + waveN * 64 + ni * 16 + l16;
            float* cp = Cout + (size_t)row * N_NODES + col;
            #pragma unroll
            for (int rr = 0; rr < 4; ++rr) cp[(size_t)rr * N_NODES] = acc[mi][ni][rr];
        }
}

// ---------------- epilogue: + cvec + keep_i*w3, log-softmax (f32x4 vectorized, in place) ----------------
__global__ __launch_bounds__(256) void k_epi(const float* __restrict__ cvec, const float* __restrict__ w3,
                                             const int* __restrict__ keep, float* __restrict__ out) {
    int i = blockIdx.x, t = threadIdx.x;
    __shared__ float redmax[4], redsum[4];
    float ki = keep[i] ? 1.f : 0.f;
    f32x4* orow = (f32x4*)(out + (size_t)i * N_NODES);
    const f32x4* cv = (const f32x4*)cvec;
    const f32x4* wv = (const f32x4*)w3;
    f32x4 v0 = orow[t] + cv[t] + ki * wv[t];
    f32x4 v1 = orow[t + 256] + cv[t + 256] + ki * wv[t + 256];
    float vmax = fmaxf(fmaxf(fmaxf(v0[0], v0[1]), fmaxf(v0[2], v0[3])),
                       fmaxf(fmaxf(v1[0], v1[1]), fmaxf(v1[2], v1[3])));
    #pragma unroll
    for (int off = 32; off; off >>= 1) vmax = fmaxf(vmax, __shfl_xor(vmax, off, 64));
    if ((t & 63) == 0) redmax[t >> 6] = vmax;
    __syncthreads();
    vmax = fmaxf(fmaxf(redmax[0], redmax[1]), fmaxf(redmax[2], redmax[3]));
    float se = 0.f;
    #pragma unroll
    for (int e = 0; e < 4; ++e) se += expf(v0[e] - vmax) + expf(v1[e] - vmax);
    #pragma unroll
    for (int off = 32; off; off >>= 1) se += __shfl_xor(se, off, 64);
    if ((t & 63) == 0) redsum[t >> 6] = se;
    __syncthreads();
    se = redsum[0] + redsum[1] + redsum[2] + redsum[3];
    float lz = vmax + logf(se);
    orow[t] = v0 - lz;
    orow[t + 256] = v1 - lz;
}

extern "C" void kernel_launch(void* const* d_in, const int* in_sizes, int n_in,
                              void* d_out, int out_size, void* d_ws, size_t ws_size,
                              hipStream_t stream) {
    const float* dist    = (const float*)d_in[0];
    const float* emb     = (const float*)d_in[1];
    const float* lin_l_w = (const float*)d_in[2];
    const float* lin_l_b = (const float*)d_in[3];
    const float* lin_r_w = (const float*)d_in[4];
    const float* edge_w  = (const float*)d_in[5];
    const float* edge_b  = (const float*)d_in[6];
    const float* comb_w  = (const float*)d_in[7];
    const float* comb_b  = (const float*)d_in[8];
    const int* stops     = (const int*)d_in[9];
    const int* wk        = (const int*)d_in[10];
    const int* vh        = (const int*)d_in[11];

    char* ws = (char*)d_ws;
    float* xn    = (float*)(ws + 0);          // 524288
    int*   keep  = (int*)(ws + 524288);       // 8192
    float* aggd  = (float*)(ws + 532480);     // 524288
    float* pref  = (float*)(ws + 1056768);    // 262144
    float* av    = (float*)(ws + 1318912);    // 8192
    float* bv    = (float*)(ws + 1327104);    // 8192
    float* cvec  = (float*)(ws + 1335296);    // 8192
    float* w3    = (float*)(ws + 1343488);    // 8192
    float* out   = (float*)d_out;

    const size_t NEED_FULL = 35432464;        // Ap_t + Bp_t + klist + knum
    const size_t NEED_FB   = 26779648;        // round-9 layout (confirmed fits)
    bool full = (ws_size >= NEED_FULL);

    // big buffers at 1351680
    u16* Ap = (u16*)(ws + 1351680);           // full: 17039360
    u16* Bp_t = (u16*)(ws + 18391040);        // full: 17039360 -> 35430400
    int* klist = full ? (int*)(ws + 35430400) : (int*)cvec;   // fallback: scratch, unused
    int* knum  = full ? (int*)(ws + 35432448) : (int*)w3;
    u16* Bp_fb = (u16*)(ws + 1351680);        // fallback: 17039360
    u16* Db_fb = (u16*)(ws + 18391040);       // fallback: 8388608 -> 26779648
    (void)NEED_FB;

    hipLaunchKernelGGL(k_keep, dim3(1),   dim3(1024), 0, stream, stops, keep, klist, knum);
    hipLaunchKernelGGL(k_xn,   dim3(512), dim3(256),  0, stream, emb, xn);
    if (full)
        hipLaunchKernelGGL(k_agg_list, dim3(2048), dim3(256), 0, stream, xn, emb, keep, klist, knum, aggd);
    else
        hipLaunchKernelGGL(k_agg_scan, dim3(2048), dim3(256), 0, stream, xn, emb, keep, aggd);
    hipLaunchKernelGGL(k_pref, dim3(256), dim3(256), 0, stream, aggd, emb, lin_l_w, lin_l_b, lin_r_w, edge_w, pref, av, bv);
    hipLaunchKernelGGL(k_cvec, dim3(8),   dim3(256), 0, stream, comb_w, comb_b, wk, vh, cvec, w3);

    if (full) {
        hipLaunchKernelGGL(k_pack_At, dim3(2048),   dim3(256), 0, stream, dist, pref, av, bv, edge_b, Ap);
        hipLaunchKernelGGL(k_pack_Bt, dim3(2048),   dim3(256), 0, stream, comb_w, Bp_t);
        hipLaunchKernelGGL(k_gemm_t,  dim3(16, 32), dim3(256), 0, stream, Ap, Bp_t, out);
    } else {
        hipLaunchKernelGGL(k_pack_B, dim3(2048),   dim3(256), 0, stream, comb_w, Bp_fb);
        hipLaunchKernelGGL(k_pack_D, dim3(2048),   dim3(256), 0, stream, dist, Db_fb);
        hipLaunchKernelGGL(k_gemm_p, dim3(16, 32), dim3(256), 0, stream, Db_fb, Bp_fb, pref, av, bv, edge_b, out);
    }
    hipLaunchKernelGGL(k_epi, dim3(2048), dim3(256), 0, stream, cvec, w3, keep, out);
}